// Round 5
// baseline (2115.179 us; speedup 1.0000x reference)
//
#include <hip/hip_runtime.h>
#include <hip/hip_fp16.h>
#include <cstddef>

// FDRNN: fuzzy -> FC(200->1024->1024->1024->128) -> 2-layer tanh RNN (H=512)
// B=64, S=512 -> 32768 rows.
//
// R8 (2nd resubmit; rounds 3+4 lost to broker timeouts): R7 post-mortem:
// VGPR_Count=128 (< 196 needed) proved the compiler REMATERIALIZED the named
// W loads inside the t-loop -> W still streamed from L2 (~1700 cyc/step) +
// 512 broadcast h-reads/CU/step (~1500 cyc). R8:
//  - amdgpu_waves_per_eu(2,2): pins backend budget to 256 VGPR/wave.
//  - asm "+v" pin per W value: cannot be rematerialized from its load.
//  - wave-j-slice: wave w owns j[64w..64w+64), lane owns o=l+64k (k=0..7).
//    h-broadcast reads drop 512->64 b128/CU/step. W: 48 j in regs (192 VGPR),
//    16 j in LDS (128KB). Cross-wave reduce via psum[8][512] (16KB), 2
//    barriers/step. Model ~1800-2200 cyc/step (from 3634).

typedef _Float16 half8 __attribute__((ext_vector_type(8)));
typedef float f32x4 __attribute__((ext_vector_type(4)));
typedef float f32v4 __attribute__((ext_vector_type(4)));
typedef _Float16 v2h __attribute__((ext_vector_type(2)));

__device__ __forceinline__ void gld_lds16(const void* g, void* lds) {
  __builtin_amdgcn_global_load_lds(
      (const __attribute__((address_space(1))) unsigned int*)g,
      (__attribute__((address_space(3))) unsigned int*)lds, 16, 0, 0);
}

// ---------------- fuzzy (fp16 out, K padded 200->256) ----------------
__global__ void fuzzy16(const float* __restrict__ x, const float* __restrict__ fp,
                        _Float16* __restrict__ z, int nrows) {
  int idx = blockIdx.x * blockDim.x + threadIdx.x;
  if (idx >= nrows * 256) return;
  int r = idx >> 8;
  int f = idx & 255;
  float v = 0.f;
  if (f < 200) {
    int i = f % 50;
    float xv = x[r * 50 + i];
    float mu = fp[2 * f];
    float sg = fp[2 * f + 1];
    float d = xv - mu;
    v = expf(-(d * d) / sg);
  }
  z[idx] = (_Float16)v;
}

// ---------------- weight fp32 -> fp16 (with optional K zero-pad) -------------
__global__ void cvt_w16(const float* __restrict__ W, _Float16* __restrict__ O,
                        int rows, int kin, int kpad) {
  int idx = blockIdx.x * blockDim.x + threadIdx.x;
  if (idx >= rows * kpad) return;
  int r = idx / kpad;
  int k = idx - r * kpad;
  O[idx] = (k < kin) ? (_Float16)W[(size_t)r * kin + k] : (_Float16)0.f;
}

// ---------------- MFMA fp16 GEMM: C16[M][N] = A16[M][K] @ W16[N][K]^T + b ----
__global__ __launch_bounds__(256) void gemm16(
    const _Float16* __restrict__ A, const _Float16* __restrict__ W,
    const float* __restrict__ b1, const float* __restrict__ b2,
    _Float16* __restrict__ C, int M, int N, int K) {
  __shared__ _Float16 As[128 * 32];
  __shared__ _Float16 Bs[128 * 32];
  const int tid = threadIdx.x;
  const int bm = blockIdx.y * 128;
  const int bn = blockIdx.x * 128;
  const int lane = tid & 63;
  const int wv = tid >> 6;
  const int wm = (wv >> 1) * 64;
  const int wn = (wv & 1) * 64;
  const int frow = lane & 15;
  const int fk = (lane >> 4) * 8;

  const int srow = tid >> 2;
  const int scol = (tid & 3) * 16;  // bytes
  const char* gA = (const char*)(A + (size_t)(bm + srow) * K) + scol;
  const char* gB = (const char*)(W + (size_t)(bn + srow) * K) + scol;
  const size_t rowstep = (size_t)64 * K * 2;
  char* lA = (char*)As + tid * 16;
  char* lB = (char*)Bs + tid * 16;

  f32x4 acc[4][4] = {};

  for (int k0 = 0; k0 < K; k0 += 32) {
    gld_lds16(gA, lA);
    gld_lds16(gA + rowstep, lA + 4096);
    gld_lds16(gB, lB);
    gld_lds16(gB + rowstep, lB + 4096);
    gA += 64;
    gB += 64;
    __syncthreads();
    half8 af[4], bf[4];
#pragma unroll
    for (int i = 0; i < 4; i++) {
      af[i] = *(const half8*)(As + (wm + i * 16 + frow) * 32 + fk);
      bf[i] = *(const half8*)(Bs + (wn + i * 16 + frow) * 32 + fk);
    }
#pragma unroll
    for (int i = 0; i < 4; i++)
#pragma unroll
      for (int j = 0; j < 4; j++)
        acc[i][j] = __builtin_amdgcn_mfma_f32_16x16x32_f16(af[i], bf[j], acc[i][j], 0, 0, 0);
    __syncthreads();
  }

  float bias[4];
#pragma unroll
  for (int j = 0; j < 4; j++) {
    int col = bn + wn + j * 16 + frow;
    bias[j] = b1[col] + (b2 ? b2[col] : 0.f);
  }
  const int r0 = (lane >> 4) * 4;
#pragma unroll
  for (int i = 0; i < 4; i++) {
#pragma unroll
    for (int r = 0; r < 4; r++) {
      int row = bm + wm + i * 16 + r0 + r;
      _Float16* Cp = C + (size_t)row * N + bn + wn + frow;
#pragma unroll
      for (int j = 0; j < 4; j++)
        Cp[j * 16] = (_Float16)(acc[i][j][r] + bias[j]);
    }
  }
}

// ---------------- RNN weight pack (fp32 -> fp16, 16B groups) ----------------
// QW[j4*512 + o] = 8 fp16 = w_hh[o][8*j4 .. 8*j4+7]
__global__ void pack_whh_fp16(const float* __restrict__ W, float4* __restrict__ QW) {
  int idx = blockIdx.x * blockDim.x + threadIdx.x;
  if (idx >= 32768) return;
  int j4 = idx >> 9;
  int o = idx & 511;
  const float* src = W + (size_t)o * 512 + j4 * 8;
  __align__(16) __half2 p[4];
#pragma unroll
  for (int k = 0; k < 4; k++)
    p[k] = __halves2half2(__float2half(src[2 * k]), __float2half(src[2 * k + 1]));
  QW[idx] = *(const float4*)p;
}

__device__ __forceinline__ float dot2acc(float wbits, float hbits, float acc) {
#if __has_builtin(__builtin_amdgcn_fdot2)
  return __builtin_amdgcn_fdot2(__builtin_bit_cast(v2h, wbits),
                                __builtin_bit_cast(v2h, hbits), acc, false);
#else
  float2 wf = __half22float2(__builtin_bit_cast(__half2, wbits));
  float2 hf = __half22float2(__builtin_bit_cast(__half2, hbits));
  return fmaf(wf.x, hf.x, fmaf(wf.y, hf.y, acc));
#endif
}

// Register W: per thread 8 o-rows (o=l+64k) x 48 j (6 groups of 8) = 48 f32x4.
// Named + asm-pinned: load cannot be rematerialized, value must stay in VGPRs.
#define DECLK(k)                                                           \
  f32x4 w##k##_0 = qb[(0 << 9) + ((k) << 6)]; asm volatile("" : "+v"(w##k##_0)); \
  f32x4 w##k##_1 = qb[(1 << 9) + ((k) << 6)]; asm volatile("" : "+v"(w##k##_1)); \
  f32x4 w##k##_2 = qb[(2 << 9) + ((k) << 6)]; asm volatile("" : "+v"(w##k##_2)); \
  f32x4 w##k##_3 = qb[(3 << 9) + ((k) << 6)]; asm volatile("" : "+v"(w##k##_3)); \
  f32x4 w##k##_4 = qb[(4 << 9) + ((k) << 6)]; asm volatile("" : "+v"(w##k##_4)); \
  f32x4 w##k##_5 = qb[(5 << 9) + ((k) << 6)]; asm volatile("" : "+v"(w##k##_5));

#define DOT1(k, g)                                  \
  acc##k = dot2acc(w##k##_##g.x, hq.x, acc##k);     \
  acc##k = dot2acc(w##k##_##g.y, hq.y, acc##k);     \
  acc##k = dot2acc(w##k##_##g.z, hq.z, acc##k);     \
  acc##k = dot2acc(w##k##_##g.w, hq.w, acc##k);

#define DOTG(g)                         \
  {                                     \
    f32v4 hq = hs4[w8 + (g)];           \
    DOT1(0, g) DOT1(1, g) DOT1(2, g)    \
    DOT1(3, g) DOT1(4, g) DOT1(5, g)    \
    DOT1(6, g) DOT1(7, g)               \
  }

#define DOTLK(gp, k)                                \
  {                                                 \
    f32v4 q = wl[((gp) << 9) + ((k) << 6)];         \
    acc##k = dot2acc(q.x, hq.x, acc##k);            \
    acc##k = dot2acc(q.y, hq.y, acc##k);            \
    acc##k = dot2acc(q.z, hq.z, acc##k);            \
    acc##k = dot2acc(q.w, hq.w, acc##k);            \
  }

#define DOTL(gp)                                    \
  {                                                 \
    f32v4 hq = hs4[w8 + 6 + (gp)];                  \
    DOTLK(gp, 0) DOTLK(gp, 1) DOTLK(gp, 2)          \
    DOTLK(gp, 3) DOTLK(gp, 4) DOTLK(gp, 5)          \
    DOTLK(gp, 6) DOTLK(gp, 7)                       \
  }

// ---------------- RNN: one block per batch, wave-j-sliced ----------------
// Wave w owns j in [64w, 64w+64); lane l owns outputs o = l + 64k, k=0..7.
// 48 j/thread in pinned VGPRs (192), 16 j/thread in LDS (128 KB block-wide).
// Per step: dots -> psum[w][o] -> barrier -> per-o reduce+tanh -> barrier.
__global__ __launch_bounds__(512) __attribute__((amdgpu_waves_per_eu(2, 2)))
void rnn_wavej_k(
    const _Float16* __restrict__ pre,  // [512][512] per batch, biases folded
    const f32v4* __restrict__ QW,      // packed fp16 w_hh [64 grp][512 o]
    float* __restrict__ out32,         // nullable: final fp32 output
    _Float16* __restrict__ out16) {    // nullable: fp16 h for next-layer GEMM
  const int b = blockIdx.x;
  const int tid = threadIdx.x;
  const int w = tid >> 6;
  const int l = tid & 63;
  const int w8 = w << 3;

  __shared__ f32v4 wlds[16][512];                // [w*2+gp][o]  128 KB
  __shared__ float psum[8][512];                 // 16 KB
  __shared__ __align__(16) __half hbuf[2][512];  // 2 KB

  // qb[g*512 + 64k] = QW[(w*8+g)*512 + (l+64k)]
  const f32v4* qb = QW + ((size_t)(w8) << 9) + l;
  DECLK(0) DECLK(1) DECLK(2) DECLK(3) DECLK(4) DECLK(5) DECLK(6) DECLK(7)

  // LDS-resident W: groups 6,7 of each wave's slice
  f32v4* wl = &wlds[w << 1][l];
#pragma unroll
  for (int gp = 0; gp < 2; gp++)
#pragma unroll
    for (int k = 0; k < 8; k++)
      wl[(gp << 9) + (k << 6)] = qb[((6 + gp) << 9) + (k << 6)];

  hbuf[0][tid] = __float2half(0.f);
  __syncthreads();

  const _Float16* preb = pre + (size_t)b * 262144;
  float* ob32 = out32 ? out32 + (size_t)b * 262144 : nullptr;
  _Float16* ob16 = out16 ? out16 + (size_t)b * 262144 : nullptr;

  _Float16 pcur = preb[tid];  // t=0 pre for o=tid, prefetched
  int p = 0;
  for (int t = 0; t < 512; t++) {
    const f32v4* hs4 = (const f32v4*)hbuf[p];
    float acc0 = 0.f, acc1 = 0.f, acc2 = 0.f, acc3 = 0.f;
    float acc4 = 0.f, acc5 = 0.f, acc6 = 0.f, acc7 = 0.f;
    DOTG(0) DOTG(1) DOTG(2) DOTG(3) DOTG(4) DOTG(5)
    DOTL(0) DOTL(1)
    // psum[w][l+64k] = acc_k  (banks: l%32 -> 2-way, free)
    float* ps = &psum[w][l];
    ps[0] = acc0;   ps[64] = acc1;  ps[128] = acc2; ps[192] = acc3;
    ps[256] = acc4; ps[320] = acc5; ps[384] = acc6; ps[448] = acc7;
    __syncthreads();  // [A] psum complete
    float s = (float)pcur;
    if (t < 511) pcur = preb[(t + 1) * 512 + tid];  // prefetch next pre
    s += psum[0][tid] + psum[1][tid] + psum[2][tid] + psum[3][tid] +
         psum[4][tid] + psum[5][tid] + psum[6][tid] + psum[7][tid];
    // fast tanh: 1 - 2/(exp(2v)+1)
    float z = __expf(2.f * s);
    float r = __builtin_amdgcn_rcpf(z + 1.f);
    float hn = fmaf(-2.f, r, 1.f);
    hbuf[p ^ 1][tid] = __float2half(hn);
    if (ob32) ob32[t * 512 + tid] = hn;
    if (ob16) ob16[t * 512 + tid] = (_Float16)hn;
    p ^= 1;
    __syncthreads();  // [B] h_t visible for next step's dots
  }
}

extern "C" void kernel_launch(void* const* d_in, const int* in_sizes, int n_in,
                              void* d_out, int out_size, void* d_ws, size_t ws_size,
                              hipStream_t stream) {
  const float* x     = (const float*)d_in[0];
  const float* fp    = (const float*)d_in[1];
  const float* fc0_w = (const float*)d_in[2];
  const float* fc0_b = (const float*)d_in[3];
  const float* fc1_w = (const float*)d_in[4];
  const float* fc1_b = (const float*)d_in[5];
  const float* fc2_w = (const float*)d_in[6];
  const float* fc2_b = (const float*)d_in[7];
  const float* fc3_w = (const float*)d_in[8];
  const float* fc3_b = (const float*)d_in[9];
  const float* w_ih0 = (const float*)d_in[10];
  const float* w_hh0 = (const float*)d_in[11];
  const float* b_ih0 = (const float*)d_in[12];
  const float* b_hh0 = (const float*)d_in[13];
  const float* w_ih1 = (const float*)d_in[14];
  const float* w_hh1 = (const float*)d_in[15];
  const float* b_ih1 = (const float*)d_in[16];
  const float* b_hh1 = (const float*)d_in[17];
  float* out = (float*)d_out;
  float* ws  = (float*)d_ws;

  // ws layout (float offsets). Total ~73.8 MB.
  _Float16* preH = (_Float16*)ws;                    // [32768][512] fp16
  float* U = ws + 8388608;
  _Float16* h16 = (_Float16*)U;                      // RNN phase: [32768][512]
  _Float16* t0  = (_Float16*)U;                      // FC phase: [8192][1024]
  float* R2 = U + 4194304;
  _Float16* t1  = (_Float16*)R2;                     // [8192][1024]
  _Float16* zc  = (_Float16*)R2;                     // [8192][256]
  _Float16* f3  = (_Float16*)(R2 + 1048576);         // [8192][128]
  float* wbase = ws + 16777216;
  float4*   QW0   = (float4*)wbase;
  float4*   QW1   = (float4*)(wbase + 131072);
  _Float16* fc0h  = (_Float16*)(wbase + 262144);
  _Float16* fc1h  = (_Float16*)(wbase + 393216);
  _Float16* fc2h  = (_Float16*)(wbase + 917504);
  _Float16* fc3h  = (_Float16*)(wbase + 1441792);
  _Float16* wih0h = (_Float16*)(wbase + 1507328);
  _Float16* wih1h = (_Float16*)(wbase + 1540096);

  pack_whh_fp16<<<128, 256, 0, stream>>>(w_hh0, QW0);
  pack_whh_fp16<<<128, 256, 0, stream>>>(w_hh1, QW1);
  cvt_w16<<<1024, 256, 0, stream>>>(fc0_w, fc0h, 1024, 200, 256);
  cvt_w16<<<4096, 256, 0, stream>>>(fc1_w, fc1h, 1024, 1024, 1024);
  cvt_w16<<<4096, 256, 0, stream>>>(fc2_w, fc2h, 1024, 1024, 1024);
  cvt_w16<<<512, 256, 0, stream>>>(fc3_w, fc3h, 128, 1024, 1024);
  cvt_w16<<<256, 256, 0, stream>>>(w_ih0, wih0h, 512, 128, 128);
  cvt_w16<<<1024, 256, 0, stream>>>(w_ih1, wih1h, 512, 512, 512);

  const int CH = 8192;  // 32768 rows in 4 chunks
  for (int c = 0; c < 4; c++) {
    size_t row0 = (size_t)c * CH;
    fuzzy16<<<CH, 256, 0, stream>>>(x + row0 * 50, fp, zc, CH);
    gemm16<<<dim3(8, 64), 256, 0, stream>>>(zc, fc0h, fc0_b, nullptr, t0, CH, 1024, 256);
    gemm16<<<dim3(8, 64), 256, 0, stream>>>(t0, fc1h, fc1_b, nullptr, t1, CH, 1024, 1024);
    gemm16<<<dim3(8, 64), 256, 0, stream>>>(t1, fc2h, fc2_b, nullptr, t0, CH, 1024, 1024);
    gemm16<<<dim3(1, 64), 256, 0, stream>>>(t0, fc3h, fc3_b, nullptr, f3, CH, 128, 1024);
    gemm16<<<dim3(4, 64), 256, 0, stream>>>(f3, wih0h, b_ih0, b_hh0,
                                            preH + row0 * 512, CH, 512, 128);
  }

  // RNN layer 0: preH -> h16 (fp16, feeds layer-1 input projection)
  rnn_wavej_k<<<64, 512, 0, stream>>>(preH, (const f32v4*)QW0, nullptr, h16);
  // pre1 = h0 @ w_ih1^T + b_ih1 + b_hh1 (fp16 out into preH)
  gemm16<<<dim3(4, 256), 256, 0, stream>>>(h16, wih1h, b_ih1, b_hh1, preH, 32768, 512, 512);
  // RNN layer 1: preH -> final fp32 output
  rnn_wavej_k<<<64, 512, 0, stream>>>(preH, (const f32v4*)QW1, out, nullptr);
}